// Round 1
// baseline (254.976 us; speedup 1.0000x reference)
//
#include <hip/hip_runtime.h>
#include <hip/hip_bf16.h>
#include <stdint.h>

typedef __attribute__((ext_vector_type(8))) short short8;
typedef __attribute__((ext_vector_type(4))) float f32x4;

static constexpr long M_ = 16384;   // 4*4096 rows of x
static constexpr long N_ = 2048;    // out_features
static constexpr long K_ = 2048;    // in_features

#define BM 128
#define BN 128
#define BK 32

#define GLOAD_LDS16(g, l)                                                          \
  __builtin_amdgcn_global_load_lds(                                               \
      (const __attribute__((address_space(1))) unsigned int*)(g),                 \
      (__attribute__((address_space(3))) unsigned int*)(l), 16, 0, 0)

// ---------------- scalar init ----------------
__global__ __launch_bounds__(64) void k_init(double* gw_sum, unsigned* gx_bits) {
  if (threadIdx.x == 0) {
    *gw_sum = 0.0;
    *gx_bits = 0u;
  }
}

// ---------------- max |x| ----------------
__global__ __launch_bounds__(256) void k_absmax(const float4* __restrict__ x, long n4,
                                                unsigned* __restrict__ gx_bits) {
  float m = 0.0f;
  const long stride = (long)gridDim.x * blockDim.x;
  for (long i = (long)blockIdx.x * blockDim.x + threadIdx.x; i < n4; i += stride) {
    float4 v = x[i];
    m = fmaxf(m, fmaxf(fmaxf(fabsf(v.x), fabsf(v.y)), fmaxf(fabsf(v.z), fabsf(v.w))));
  }
#pragma unroll
  for (int off = 32; off > 0; off >>= 1) m = fmaxf(m, __shfl_down(m, off));
  __shared__ float sm[4];
  const int lane = threadIdx.x & 63, wv = threadIdx.x >> 6;
  if (lane == 0) sm[wv] = m;
  __syncthreads();
  if (threadIdx.x == 0) {
    float bm = fmaxf(fmaxf(sm[0], sm[1]), fmaxf(sm[2], sm[3]));
    // all values >= 0: uint bit-pattern order == float order
    atomicMax(gx_bits, __float_as_uint(bm));
  }
}

// ---------------- sum |W| (f64 for accuracy of mean) ----------------
__global__ __launch_bounds__(256) void k_abssum(const float4* __restrict__ w, long n4,
                                                double* __restrict__ gw_sum) {
  double s = 0.0;
  const long stride = (long)gridDim.x * blockDim.x;
  for (long i = (long)blockIdx.x * blockDim.x + threadIdx.x; i < n4; i += stride) {
    float4 v = w[i];
    s += (double)fabsf(v.x) + (double)fabsf(v.y) + (double)fabsf(v.z) + (double)fabsf(v.w);
  }
#pragma unroll
  for (int off = 32; off > 0; off >>= 1) s += __shfl_down(s, off);
  __shared__ double sd[4];
  const int lane = threadIdx.x & 63, wv = threadIdx.x >> 6;
  if (lane == 0) sd[wv] = s;
  __syncthreads();
  if (threadIdx.x == 0) atomicAdd(gw_sum, (sd[0] + sd[1]) + (sd[2] + sd[3]));
}

__device__ inline unsigned short f32_to_bf16_exact(float f) {
  // exact for integer-valued floats with |v| <= 127 (<= 8 significand bits)
  return (unsigned short)(__float_as_uint(f) >> 16);
}

// ---------------- quantize x -> bf16 integers in [-127,127] ----------------
__global__ __launch_bounds__(256) void k_quant_x(const float4* __restrict__ x,
                                                 short4* __restrict__ xq, long n4,
                                                 const unsigned* __restrict__ gx_bits) {
  const double gx = (double)fmaxf(__uint_as_float(*gx_bits), 1e-8f);
  const double scale = 127.0 / gx;
  const long stride = (long)gridDim.x * blockDim.x;
  for (long i = (long)blockIdx.x * blockDim.x + threadIdx.x; i < n4; i += stride) {
    float4 v = x[i];
    short4 o;
    double r;
    r = fmin(fmax(rint((double)v.x * scale), -127.0), 127.0);
    o.x = (short)f32_to_bf16_exact((float)r);
    r = fmin(fmax(rint((double)v.y * scale), -127.0), 127.0);
    o.y = (short)f32_to_bf16_exact((float)r);
    r = fmin(fmax(rint((double)v.z * scale), -127.0), 127.0);
    o.z = (short)f32_to_bf16_exact((float)r);
    r = fmin(fmax(rint((double)v.w * scale), -127.0), 127.0);
    o.w = (short)f32_to_bf16_exact((float)r);
    xq[i] = o;
  }
}

// ---------------- quantize W -> bf16 ternary {-1,0,1} ----------------
__global__ __launch_bounds__(256) void k_quant_w(const float4* __restrict__ w,
                                                 short4* __restrict__ wq, long n4,
                                                 const double* __restrict__ gw_sum) {
  const double gw = fmax(*gw_sum * (1.0 / 4194304.0), 1e-8);  // mean over 2048*2048
  const long stride = (long)gridDim.x * blockDim.x;
  for (long i = (long)blockIdx.x * blockDim.x + threadIdx.x; i < n4; i += stride) {
    float4 v = w[i];
    short4 o;
    double r;
    r = fmin(fmax(rint((double)v.x / gw), -1.0), 1.0);
    o.x = (short)f32_to_bf16_exact((float)r);
    r = fmin(fmax(rint((double)v.y / gw), -1.0), 1.0);
    o.y = (short)f32_to_bf16_exact((float)r);
    r = fmin(fmax(rint((double)v.z / gw), -1.0), 1.0);
    o.z = (short)f32_to_bf16_exact((float)r);
    r = fmin(fmax(rint((double)v.w / gw), -1.0), 1.0);
    o.w = (short)f32_to_bf16_exact((float)r);
    wq[i] = o;
  }
}

// ---------------- GEMM: out[M][N] = (Aq[M][K] . Bq[N][K]^T) * alpha + bias ----
// m97 structure: 128x128 tile, BK=32, 4 waves (2x2), global_load_lds width 16,
// 16x16x32 bf16 MFMA, 4x4 frags per wave.
__global__ __launch_bounds__(256, 2) void k_gemm(
    const short* __restrict__ Aq, const short* __restrict__ Bq,
    const float* __restrict__ bias, float* __restrict__ out,
    const unsigned* __restrict__ gx_bits, const double* __restrict__ gw_sum) {
  __shared__ short As[BM * BK];
  __shared__ short Bs[BN * BK];

  const int tid = threadIdx.x;
  const int lane = tid & 63;
  const int wv = tid >> 6;
  const int wr = wv >> 1;  // 0..1 : wave row
  const int wc = wv & 1;   // 0..1 : wave col

  const int nblocks_n = (int)(N_ / BN);  // 16
  const int nblk = (int)(blockIdx.x % nblocks_n);
  const int mblk = (int)(blockIdx.x / nblocks_n);
  const long brow = (long)mblk * BM;
  const long bcol = (long)nblk * BN;

  f32x4 acc[4][4];
#pragma unroll
  for (int m = 0; m < 4; m++)
#pragma unroll
    for (int n = 0; n < 4; n++) acc[m][n] = (f32x4){0.f, 0.f, 0.f, 0.f};

  // staging: 512 chunks of 16B per tile; chunk ch -> row ch>>2, k-off (ch&3)*8
  const int ch0 = tid;
  const int ch1 = tid + 256;
  const short* A0 = Aq + (brow + (ch0 >> 2)) * K_ + (ch0 & 3) * 8;
  const short* A1 = Aq + (brow + (ch1 >> 2)) * K_ + (ch1 & 3) * 8;
  const short* B0 = Bq + (bcol + (ch0 >> 2)) * K_ + (ch0 & 3) * 8;
  const short* B1 = Bq + (bcol + (ch1 >> 2)) * K_ + (ch1 & 3) * 8;
  short* lA0 = &As[ch0 * 8];
  short* lA1 = &As[ch1 * 8];
  short* lB0 = &Bs[ch0 * 8];
  short* lB1 = &Bs[ch1 * 8];

  const int koff = (lane >> 4) * 8;
  const int rsel = lane & 15;

  for (int kt = 0; kt < (int)K_; kt += BK) {
    GLOAD_LDS16(A0 + kt, lA0);
    GLOAD_LDS16(A1 + kt, lA1);
    GLOAD_LDS16(B0 + kt, lB0);
    GLOAD_LDS16(B1 + kt, lB1);
    __syncthreads();  // drains vmcnt before barrier

    short8 a[4], b[4];
#pragma unroll
    for (int m = 0; m < 4; m++)
      a[m] = *(const short8*)(&As[(wr * 64 + m * 16 + rsel) * BK + koff]);
#pragma unroll
    for (int n = 0; n < 4; n++)
      b[n] = *(const short8*)(&Bs[(wc * 64 + n * 16 + rsel) * BK + koff]);

#pragma unroll
    for (int m = 0; m < 4; m++)
#pragma unroll
      for (int n = 0; n < 4; n++)
        acc[m][n] = __builtin_amdgcn_mfma_f32_16x16x32_bf16(a[m], b[n], acc[m][n], 0, 0, 0);
    __syncthreads();
  }

  const float gxf = fmaxf(__uint_as_float(*gx_bits), 1e-8f);
  const double gwd = fmax(*gw_sum * (1.0 / 4194304.0), 1e-8);
  const float alpha = (float)((double)gxf * gwd * (1.0 / 127.0));

#pragma unroll
  for (int n = 0; n < 4; n++) {
    const long col = bcol + wc * 64 + n * 16 + (lane & 15);
    const float bv = bias[col];
#pragma unroll
    for (int m = 0; m < 4; m++) {
      const long row0 = brow + wr * 64 + m * 16 + (lane >> 4) * 4;
#pragma unroll
      for (int r = 0; r < 4; r++) {
        out[(row0 + r) * N_ + col] = acc[m][n][r] * alpha + bv;
      }
    }
  }
}

extern "C" void kernel_launch(void* const* d_in, const int* in_sizes, int n_in,
                              void* d_out, int out_size, void* d_ws, size_t ws_size,
                              hipStream_t stream) {
  const float* x = (const float*)d_in[0];
  const float* W = (const float*)d_in[1];
  const float* b = (const float*)d_in[2];
  float* out = (float*)d_out;

  char* ws = (char*)d_ws;
  double* gw_sum = (double*)ws;            // 8 B
  unsigned* gx_bits = (unsigned*)(ws + 8); // 4 B
  short* xq = (short*)(ws + 256);                                  // M*K bf16 = 64 MiB
  short* wq = (short*)(ws + 256 + (size_t)M_ * (size_t)K_ * 2);    // N*K bf16 = 8 MiB

  const long nx4 = M_ * K_ / 4;  // 8,388,608
  const long nw4 = N_ * K_ / 4;  // 1,048,576

  hipLaunchKernelGGL(k_init, dim3(1), dim3(64), 0, stream, gw_sum, gx_bits);
  hipLaunchKernelGGL(k_absmax, dim3(2048), dim3(256), 0, stream,
                     (const float4*)x, nx4, gx_bits);
  hipLaunchKernelGGL(k_abssum, dim3(512), dim3(256), 0, stream,
                     (const float4*)W, nw4, gw_sum);
  hipLaunchKernelGGL(k_quant_x, dim3(2048), dim3(256), 0, stream,
                     (const float4*)x, (short4*)xq, nx4, gx_bits);
  hipLaunchKernelGGL(k_quant_w, dim3(512), dim3(256), 0, stream,
                     (const float4*)W, (short4*)wq, nw4, gw_sum);
  hipLaunchKernelGGL(k_gemm, dim3((unsigned)((M_ / BM) * (N_ / BN))), dim3(256), 0, stream,
                     xq, wq, b, out, gx_bits, gw_sum);
}

// Round 2
// 180.168 us; speedup vs baseline: 1.4152x; 1.4152x over previous
//
#include <hip/hip_runtime.h>
#include <hip/hip_bf16.h>
#include <stdint.h>

typedef __attribute__((ext_vector_type(4))) int i32x4;

static constexpr long M_ = 16384;   // 4*4096 rows of x
static constexpr long N_ = 2048;    // out_features
static constexpr long K_ = 2048;    // in_features

#define BM 128
#define BN 128
#define BKB 64   // K-bytes per tile (64 i8 values)

#define GLOAD_LDS16(g, l)                                                          \
  __builtin_amdgcn_global_load_lds(                                               \
      (const __attribute__((address_space(1))) unsigned int*)(g),                 \
      (__attribute__((address_space(3))) unsigned int*)(l), 16, 0, 0)

// ---------------- scalar init ----------------
__global__ __launch_bounds__(64) void k_init(double* gw_sum, unsigned* gx_bits) {
  if (threadIdx.x == 0) {
    *gw_sum = 0.0;
    *gx_bits = 0u;
  }
}

// ---------------- max |x| ----------------
__global__ __launch_bounds__(256) void k_absmax(const float4* __restrict__ x, long n4,
                                                unsigned* __restrict__ gx_bits) {
  float m = 0.0f;
  const long stride = (long)gridDim.x * blockDim.x;
  for (long i = (long)blockIdx.x * blockDim.x + threadIdx.x; i < n4; i += stride) {
    float4 v = x[i];
    m = fmaxf(m, fmaxf(fmaxf(fabsf(v.x), fabsf(v.y)), fmaxf(fabsf(v.z), fabsf(v.w))));
  }
#pragma unroll
  for (int off = 32; off > 0; off >>= 1) m = fmaxf(m, __shfl_down(m, off));
  __shared__ float sm[4];
  const int lane = threadIdx.x & 63, wv = threadIdx.x >> 6;
  if (lane == 0) sm[wv] = m;
  __syncthreads();
  if (threadIdx.x == 0) {
    float bm = fmaxf(fmaxf(sm[0], sm[1]), fmaxf(sm[2], sm[3]));
    atomicMax(gx_bits, __float_as_uint(bm));  // all >=0: uint order == float order
  }
}

// ---------------- sum |W| (f64 for exact-ish mean) ----------------
__global__ __launch_bounds__(256) void k_abssum(const float4* __restrict__ w, long n4,
                                                double* __restrict__ gw_sum) {
  double s = 0.0;
  const long stride = (long)gridDim.x * blockDim.x;
  for (long i = (long)blockIdx.x * blockDim.x + threadIdx.x; i < n4; i += stride) {
    float4 v = w[i];
    s += (double)fabsf(v.x) + (double)fabsf(v.y) + (double)fabsf(v.z) + (double)fabsf(v.w);
  }
#pragma unroll
  for (int off = 32; off > 0; off >>= 1) s += __shfl_down(s, off);
  __shared__ double sd[4];
  const int lane = threadIdx.x & 63, wv = threadIdx.x >> 6;
  if (lane == 0) sd[wv] = s;
  __syncthreads();
  if (threadIdx.x == 0) atomicAdd(gw_sum, (sd[0] + sd[1]) + (sd[2] + sd[3]));
}

// ---------------- quantize x -> int8 in [-127,127] ----------------
__global__ __launch_bounds__(256) void k_quant_x(const float4* __restrict__ x,
                                                 char4* __restrict__ xq, long n4,
                                                 const unsigned* __restrict__ gx_bits) {
  const double gx = (double)fmaxf(__uint_as_float(*gx_bits), 1e-8f);
  const double scale = 127.0 / gx;
  const long stride = (long)gridDim.x * blockDim.x;
  for (long i = (long)blockIdx.x * blockDim.x + threadIdx.x; i < n4; i += stride) {
    float4 v = x[i];
    char4 o;
    o.x = (signed char)(int)fmin(fmax(rint((double)v.x * scale), -127.0), 127.0);
    o.y = (signed char)(int)fmin(fmax(rint((double)v.y * scale), -127.0), 127.0);
    o.z = (signed char)(int)fmin(fmax(rint((double)v.z * scale), -127.0), 127.0);
    o.w = (signed char)(int)fmin(fmax(rint((double)v.w * scale), -127.0), 127.0);
    xq[i] = o;
  }
}

// ---------------- quantize W -> int8 ternary {-1,0,1} ----------------
__global__ __launch_bounds__(256) void k_quant_w(const float4* __restrict__ w,
                                                 char4* __restrict__ wq, long n4,
                                                 const double* __restrict__ gw_sum) {
  const double gw = fmax(*gw_sum * (1.0 / 4194304.0), 1e-8);  // mean over 2048*2048
  const long stride = (long)gridDim.x * blockDim.x;
  for (long i = (long)blockIdx.x * blockDim.x + threadIdx.x; i < n4; i += stride) {
    float4 v = w[i];
    char4 o;
    o.x = (signed char)(int)fmin(fmax(rint((double)v.x / gw), -1.0), 1.0);
    o.y = (signed char)(int)fmin(fmax(rint((double)v.y / gw), -1.0), 1.0);
    o.z = (signed char)(int)fmin(fmax(rint((double)v.z / gw), -1.0), 1.0);
    o.w = (signed char)(int)fmin(fmax(rint((double)v.w / gw), -1.0), 1.0);
    wq[i] = o;
  }
}

// ---------------- GEMM: out[M][N] = (Aq[M][K] . Bq[N][K]^T) * alpha + bias ----
// m97 structure on the i8 pipe: 128x128 tile, BK=64 i8, 4 waves (2x2),
// global_load_lds width 16, mfma_i32_16x16x64_i8, 4x4 frags per wave.
// XCD-aware bijective swizzle (nwg=2048, %8==0).
__global__ __launch_bounds__(256, 2) void k_gemm(
    const signed char* __restrict__ Aq, const signed char* __restrict__ Bq,
    const float* __restrict__ bias, float* __restrict__ out,
    const unsigned* __restrict__ gx_bits, const double* __restrict__ gw_sum) {
  __shared__ signed char As[BM * BKB];  // 8 KiB
  __shared__ signed char Bs[BN * BKB];  // 8 KiB

  const int tid = threadIdx.x;
  const int lane = tid & 63;
  const int wv = tid >> 6;
  const int wr = wv >> 1;  // wave row 0..1
  const int wc = wv & 1;   // wave col 0..1

  // XCD swizzle: nwg = 2048, 8 XCDs, 256 contiguous work-ids per XCD
  const int wg = (int)((blockIdx.x & 7) * 256 + (blockIdx.x >> 3));
  const int nblocks_n = (int)(N_ / BN);  // 16
  const int nblk = wg % nblocks_n;
  const int mblk = wg / nblocks_n;
  const long brow = (long)mblk * BM;
  const long bcol = (long)nblk * BN;

  i32x4 acc[4][4];
#pragma unroll
  for (int m = 0; m < 4; m++)
#pragma unroll
    for (int n = 0; n < 4; n++) acc[m][n] = (i32x4){0, 0, 0, 0};

  // staging: tile = 128 rows x 64 B = 512 chunks of 16B; chunk ch -> row ch>>2,
  // byte-off (ch&3)*16
  const int ch0 = tid;
  const int ch1 = tid + 256;
  const signed char* A0 = Aq + (brow + (ch0 >> 2)) * K_ + (ch0 & 3) * 16;
  const signed char* A1 = Aq + (brow + (ch1 >> 2)) * K_ + (ch1 & 3) * 16;
  const signed char* B0 = Bq + (bcol + (ch0 >> 2)) * K_ + (ch0 & 3) * 16;
  const signed char* B1 = Bq + (bcol + (ch1 >> 2)) * K_ + (ch1 & 3) * 16;
  signed char* lA0 = &As[ch0 * 16];
  signed char* lA1 = &As[ch1 * 16];
  signed char* lB0 = &Bs[ch0 * 16];
  signed char* lB1 = &Bs[ch1 * 16];

  const int koff = (lane >> 4) * 16;  // 16 i8 per lane-group
  const int rsel = lane & 15;

  for (int kt = 0; kt < (int)K_; kt += BKB) {
    GLOAD_LDS16(A0 + kt, lA0);
    GLOAD_LDS16(A1 + kt, lA1);
    GLOAD_LDS16(B0 + kt, lB0);
    GLOAD_LDS16(B1 + kt, lB1);
    __syncthreads();  // drains vmcnt before barrier

    i32x4 a[4], b[4];
#pragma unroll
    for (int m = 0; m < 4; m++)
      a[m] = *(const i32x4*)(&As[(wr * 64 + m * 16 + rsel) * BKB + koff]);
#pragma unroll
    for (int n = 0; n < 4; n++)
      b[n] = *(const i32x4*)(&Bs[(wc * 64 + n * 16 + rsel) * BKB + koff]);

#pragma unroll
    for (int m = 0; m < 4; m++)
#pragma unroll
      for (int n = 0; n < 4; n++)
        acc[m][n] = __builtin_amdgcn_mfma_i32_16x16x64_i8(a[m], b[n], acc[m][n], 0, 0, 0);
    __syncthreads();
  }

  const float gxf = fmaxf(__uint_as_float(*gx_bits), 1e-8f);
  const double gwd = fmax(*gw_sum * (1.0 / 4194304.0), 1e-8);
  const float alpha = (float)((double)gxf * gwd * (1.0 / 127.0));

#pragma unroll
  for (int n = 0; n < 4; n++) {
    const long col = bcol + wc * 64 + n * 16 + (lane & 15);
    const float bv = bias[col];
#pragma unroll
    for (int m = 0; m < 4; m++) {
      const long row0 = brow + wr * 64 + m * 16 + (lane >> 4) * 4;
#pragma unroll
      for (int r = 0; r < 4; r++) {
        out[(row0 + r) * N_ + col] = (float)acc[m][n][r] * alpha + bv;
      }
    }
  }
}

extern "C" void kernel_launch(void* const* d_in, const int* in_sizes, int n_in,
                              void* d_out, int out_size, void* d_ws, size_t ws_size,
                              hipStream_t stream) {
  const float* x = (const float*)d_in[0];
  const float* W = (const float*)d_in[1];
  const float* b = (const float*)d_in[2];
  float* out = (float*)d_out;

  char* ws = (char*)d_ws;
  double* gw_sum = (double*)ws;            // 8 B
  unsigned* gx_bits = (unsigned*)(ws + 8); // 4 B
  signed char* xq = (signed char*)(ws + 256);                            // M*K i8 = 32 MiB
  signed char* wq = (signed char*)(ws + 256 + (size_t)M_ * (size_t)K_);  // N*K i8 = 4 MiB

  const long nx4 = M_ * K_ / 4;  // 8,388,608
  const long nw4 = N_ * K_ / 4;  // 1,048,576

  hipLaunchKernelGGL(k_init, dim3(1), dim3(64), 0, stream, gw_sum, gx_bits);
  hipLaunchKernelGGL(k_absmax, dim3(2048), dim3(256), 0, stream,
                     (const float4*)x, nx4, gx_bits);
  hipLaunchKernelGGL(k_abssum, dim3(512), dim3(256), 0, stream,
                     (const float4*)W, nw4, gw_sum);
  hipLaunchKernelGGL(k_quant_x, dim3(2048), dim3(256), 0, stream,
                     (const float4*)x, (char4*)xq, nx4, gx_bits);
  hipLaunchKernelGGL(k_quant_w, dim3(512), dim3(256), 0, stream,
                     (const float4*)W, (char4*)wq, nw4, gw_sum);
  hipLaunchKernelGGL(k_gemm, dim3((unsigned)((M_ / BM) * (N_ / BN))), dim3(256), 0, stream,
                     xq, wq, b, out, gx_bits, gw_sum);
}

// Round 3
// 171.007 us; speedup vs baseline: 1.4910x; 1.0536x over previous
//
#include <hip/hip_runtime.h>
#include <hip/hip_bf16.h>
#include <stdint.h>

typedef __attribute__((ext_vector_type(4))) int i32x4;

static constexpr long M_ = 16384;   // 4*4096 rows of x
static constexpr long N_ = 2048;    // out_features
static constexpr long K_ = 2048;    // in_features

// ---- 256x256 8-phase i8 GEMM geometry ----
// BM=BN=256, BK=128 i8. 8 waves (2M x 4N), 512 threads.
// LDS: A[2 buf][2 ks][256 rows][64 B] + B[same] = 128 KiB dynamic.
// Per iter: 2 K-tiles, 8 phases, each {ds_read subtile | stage 1 quarter |
// barrier | lgkmcnt(0) | setprio(1) 16 MFMA setprio(0) | [vmcnt(8)] barrier}.

#define GLOAD_LDS16(g, l)                                                          \
  __builtin_amdgcn_global_load_lds(                                               \
      (const __attribute__((address_space(1))) unsigned int*)(g),                 \
      (__attribute__((address_space(3))) unsigned int*)(l), 16, 0, 0)

// ---------------- scalar init ----------------
__global__ __launch_bounds__(64) void k_init(double* gw_sum, unsigned* gx_bits) {
  if (threadIdx.x == 0) {
    *gw_sum = 0.0;
    *gx_bits = 0u;
  }
}

// ---------------- max |x| ----------------
__global__ __launch_bounds__(256) void k_absmax(const float4* __restrict__ x, long n4,
                                                unsigned* __restrict__ gx_bits) {
  float m = 0.0f;
  const long stride = (long)gridDim.x * blockDim.x;
  for (long i = (long)blockIdx.x * blockDim.x + threadIdx.x; i < n4; i += stride) {
    float4 v = x[i];
    m = fmaxf(m, fmaxf(fmaxf(fabsf(v.x), fabsf(v.y)), fmaxf(fabsf(v.z), fabsf(v.w))));
  }
#pragma unroll
  for (int off = 32; off > 0; off >>= 1) m = fmaxf(m, __shfl_down(m, off));
  __shared__ float sm[4];
  const int lane = threadIdx.x & 63, wv = threadIdx.x >> 6;
  if (lane == 0) sm[wv] = m;
  __syncthreads();
  if (threadIdx.x == 0) {
    float bm = fmaxf(fmaxf(sm[0], sm[1]), fmaxf(sm[2], sm[3]));
    atomicMax(gx_bits, __float_as_uint(bm));  // all >=0: uint order == float order
  }
}

// ---------------- sum |W| (f64) ----------------
__global__ __launch_bounds__(256) void k_abssum(const float4* __restrict__ w, long n4,
                                                double* __restrict__ gw_sum) {
  double s = 0.0;
  const long stride = (long)gridDim.x * blockDim.x;
  for (long i = (long)blockIdx.x * blockDim.x + threadIdx.x; i < n4; i += stride) {
    float4 v = w[i];
    s += (double)fabsf(v.x) + (double)fabsf(v.y) + (double)fabsf(v.z) + (double)fabsf(v.w);
  }
#pragma unroll
  for (int off = 32; off > 0; off >>= 1) s += __shfl_down(s, off);
  __shared__ double sd[4];
  const int lane = threadIdx.x & 63, wv = threadIdx.x >> 6;
  if (lane == 0) sd[wv] = s;
  __syncthreads();
  if (threadIdx.x == 0) atomicAdd(gw_sum, (sd[0] + sd[1]) + (sd[2] + sd[3]));
}

// ---------------- quantize x -> int8 in [-127,127] ----------------
__global__ __launch_bounds__(256) void k_quant_x(const float4* __restrict__ x,
                                                 char4* __restrict__ xq, long n4,
                                                 const unsigned* __restrict__ gx_bits) {
  const double gx = (double)fmaxf(__uint_as_float(*gx_bits), 1e-8f);
  const double scale = 127.0 / gx;
  const long stride = (long)gridDim.x * blockDim.x;
  for (long i = (long)blockIdx.x * blockDim.x + threadIdx.x; i < n4; i += stride) {
    float4 v = x[i];
    char4 o;
    o.x = (signed char)(int)fmin(fmax(rint((double)v.x * scale), -127.0), 127.0);
    o.y = (signed char)(int)fmin(fmax(rint((double)v.y * scale), -127.0), 127.0);
    o.z = (signed char)(int)fmin(fmax(rint((double)v.z * scale), -127.0), 127.0);
    o.w = (signed char)(int)fmin(fmax(rint((double)v.w * scale), -127.0), 127.0);
    xq[i] = o;
  }
}

// ---------------- quantize W -> int8 ternary {-1,0,1} ----------------
__global__ __launch_bounds__(256) void k_quant_w(const float4* __restrict__ w,
                                                 char4* __restrict__ wq, long n4,
                                                 const double* __restrict__ gw_sum) {
  const double gw = fmax(*gw_sum * (1.0 / 4194304.0), 1e-8);  // mean over 2048*2048
  const long stride = (long)gridDim.x * blockDim.x;
  for (long i = (long)blockIdx.x * blockDim.x + threadIdx.x; i < n4; i += stride) {
    float4 v = w[i];
    char4 o;
    o.x = (signed char)(int)fmin(fmax(rint((double)v.x / gw), -1.0), 1.0);
    o.y = (signed char)(int)fmin(fmax(rint((double)v.y / gw), -1.0), 1.0);
    o.z = (signed char)(int)fmin(fmax(rint((double)v.z / gw), -1.0), 1.0);
    o.w = (signed char)(int)fmin(fmax(rint((double)v.w / gw), -1.0), 1.0);
    wq[i] = o;
  }
}

// ================= 8-phase GEMM =================
// LDS region (isb, buf, ks): offset = isb*65536 + buf*32768 + ks*16384, 16 KiB each.
// Swizzle: row r's logical 16B-chunk c stored at physical chunk c ^ ((r>>1)&3).

__device__ __forceinline__ void stageq(signed char* lds, const signed char* gp,
                                       int isb, int buf, int ks, int kbase, int tid) {
  signed char* lr = lds + isb * 65536 + buf * 32768 + ks * 16384;
  const int w = tid >> 6, lane = tid & 63;
#pragma unroll
  for (int s = 0; s < 2; ++s) {
    const int slot = w * 2 + s;
    const int r = slot * 16 + (lane >> 2);
    const int c = (lane & 3) ^ ((r >> 1) & 3);
    GLOAD_LDS16(gp + (long)r * K_ + kbase + c * 16, lr + slot * 1024);
  }
}

__device__ __forceinline__ i32x4 lds_frag(const signed char* region, int row, int lane) {
  const int swz = (((lane >> 4) ^ ((row >> 1) & 3)) << 4);
  return *(const i32x4*)(region + row * 64 + swz);
}

template <int BUF, int KS, int MH, int SGB, int SGBUF, int SGKS, int VM>
__device__ __forceinline__ void phase(signed char* lds, const signed char* Ap,
                                      const signed char* Bp, int sg_kbase, int wave_m,
                                      int wave_n, int lane, int tid,
                                      i32x4 acc[8][4], i32x4 b4[4]) {
  const signed char* Ar = lds + BUF * 32768 + KS * 16384;
  const signed char* Br = lds + 65536 + BUF * 32768 + KS * 16384;
  i32x4 a4[4];
  if (MH == 0) {
#pragma unroll
    for (int n = 0; n < 4; ++n)
      b4[n] = lds_frag(Br, wave_n * 64 + n * 16 + (lane & 15), lane);
  }
#pragma unroll
  for (int mm = 0; mm < 4; ++mm)
    a4[mm] = lds_frag(Ar, wave_m * 128 + MH * 64 + mm * 16 + (lane & 15), lane);

  stageq(lds, SGB ? Bp : Ap, SGB, SGBUF, SGKS, sg_kbase, tid);

  __builtin_amdgcn_s_barrier();
  asm volatile("s_waitcnt lgkmcnt(0)" ::: "memory");
  __builtin_amdgcn_s_setprio(1);
#pragma unroll
  for (int mm = 0; mm < 4; ++mm)
#pragma unroll
    for (int n = 0; n < 4; ++n)
      acc[MH * 4 + mm][n] =
          __builtin_amdgcn_mfma_i32_16x16x64_i8(a4[mm], b4[n], acc[MH * 4 + mm][n], 0, 0, 0);
  __builtin_amdgcn_s_setprio(0);
  if (VM) asm volatile("s_waitcnt vmcnt(8)" ::: "memory");
  __builtin_amdgcn_s_barrier();
}

__global__ __launch_bounds__(512, 2) void k_gemm(
    const signed char* __restrict__ Aq, const signed char* __restrict__ Bq,
    const float* __restrict__ bias, float* __restrict__ out,
    const unsigned* __restrict__ gx_bits, const double* __restrict__ gw_sum) {
  extern __shared__ signed char lds[];

  const int tid = threadIdx.x;
  const int lane = tid & 63;
  const int wid = tid >> 6;
  const int wave_m = wid >> 2;  // 0..1
  const int wave_n = wid & 3;   // 0..3

  // XCD swizzle: nwg = 512, 8 XCDs, 64 contiguous work-ids per XCD
  const int wg = (int)((blockIdx.x & 7) * 64 + (blockIdx.x >> 3));
  const int nblk = wg & 7;   // N_/256 = 8
  const int mblk = wg >> 3;  // 0..63
  const long brow = (long)mblk * 256;
  const long bcol = (long)nblk * 256;

  const signed char* Ap = Aq + brow * K_;
  const signed char* Bp = Bq + bcol * K_;

  i32x4 acc[8][4];
#pragma unroll
  for (int m = 0; m < 8; m++)
#pragma unroll
    for (int n = 0; n < 4; n++) acc[m][n] = (i32x4){0, 0, 0, 0};
  i32x4 b4[4];

  // prologue: tile0 full, tile1 ks0
  stageq(lds, Ap, 0, 0, 0, 0, tid);
  stageq(lds, Bp, 1, 0, 0, 0, tid);
  stageq(lds, Ap, 0, 0, 1, 64, tid);
  stageq(lds, Bp, 1, 0, 1, 64, tid);
  stageq(lds, Ap, 0, 1, 0, 128, tid);
  stageq(lds, Bp, 1, 1, 0, 128, tid);
  asm volatile("s_waitcnt vmcnt(0)" ::: "memory");
  __builtin_amdgcn_s_barrier();

  for (int kt = 0; kt < (int)K_; kt += 256) {
    const int k1 = (kt + 128) & 2047;  // tile t+1
    const int k2 = (kt + 256) & 2047;  // tile t+2 (wraps harmlessly on last iter)
    const int k3 = (kt + 384) & 2047;  // tile t+3
    phase<0, 0, 0, 0, 1, 1, 0>(lds, Ap, Bp, k1 + 64, wave_m, wave_n, lane, tid, acc, b4);
    phase<0, 0, 1, 1, 1, 1, 1>(lds, Ap, Bp, k1 + 64, wave_m, wave_n, lane, tid, acc, b4);
    phase<0, 1, 0, 0, 0, 0, 0>(lds, Ap, Bp, k2, wave_m, wave_n, lane, tid, acc, b4);
    phase<0, 1, 1, 1, 0, 0, 1>(lds, Ap, Bp, k2, wave_m, wave_n, lane, tid, acc, b4);
    phase<1, 0, 0, 0, 0, 1, 0>(lds, Ap, Bp, k2 + 64, wave_m, wave_n, lane, tid, acc, b4);
    phase<1, 0, 1, 1, 0, 1, 1>(lds, Ap, Bp, k2 + 64, wave_m, wave_n, lane, tid, acc, b4);
    phase<1, 1, 0, 0, 1, 0, 0>(lds, Ap, Bp, k3, wave_m, wave_n, lane, tid, acc, b4);
    phase<1, 1, 1, 1, 1, 0, 1>(lds, Ap, Bp, k3, wave_m, wave_n, lane, tid, acc, b4);
  }

  const float gxf = fmaxf(__uint_as_float(*gx_bits), 1e-8f);
  const double gwd = fmax(*gw_sum * (1.0 / 4194304.0), 1e-8);
  const float alpha = (float)((double)gxf * gwd * (1.0 / 127.0));

#pragma unroll
  for (int n = 0; n < 4; ++n) {
    const long col = bcol + wave_n * 64 + n * 16 + (lane & 15);
    const float bv = bias[col];
#pragma unroll
    for (int m = 0; m < 8; ++m) {
      const long row0 = brow + wave_m * 128 + m * 16 + (lane >> 4) * 4;
#pragma unroll
      for (int r = 0; r < 4; ++r) {
        out[(row0 + r) * N_ + col] = (float)acc[m][n][r] * alpha + bv;
      }
    }
  }
}

extern "C" void kernel_launch(void* const* d_in, const int* in_sizes, int n_in,
                              void* d_out, int out_size, void* d_ws, size_t ws_size,
                              hipStream_t stream) {
  const float* x = (const float*)d_in[0];
  const float* W = (const float*)d_in[1];
  const float* b = (const float*)d_in[2];
  float* out = (float*)d_out;

  char* ws = (char*)d_ws;
  double* gw_sum = (double*)ws;            // 8 B
  unsigned* gx_bits = (unsigned*)(ws + 8); // 4 B
  signed char* xq = (signed char*)(ws + 256);                            // M*K i8 = 32 MiB
  signed char* wq = (signed char*)(ws + 256 + (size_t)M_ * (size_t)K_);  // N*K i8 = 4 MiB

  const long nx4 = M_ * K_ / 4;
  const long nw4 = N_ * K_ / 4;

  static bool attr_set = false;
  if (!attr_set) {
    (void)hipFuncSetAttribute(reinterpret_cast<const void*>(&k_gemm),
                              hipFuncAttributeMaxDynamicSharedMemorySize, 131072);
    attr_set = true;
  }

  hipLaunchKernelGGL(k_init, dim3(1), dim3(64), 0, stream, gw_sum, gx_bits);
  hipLaunchKernelGGL(k_absmax, dim3(2048), dim3(256), 0, stream,
                     (const float4*)x, nx4, gx_bits);
  hipLaunchKernelGGL(k_abssum, dim3(512), dim3(256), 0, stream,
                     (const float4*)W, nw4, gw_sum);
  hipLaunchKernelGGL(k_quant_x, dim3(2048), dim3(256), 0, stream,
                     (const float4*)x, (char4*)xq, nx4, gx_bits);
  hipLaunchKernelGGL(k_quant_w, dim3(512), dim3(256), 0, stream,
                     (const float4*)W, (char4*)wq, nw4, gw_sum);
  hipLaunchKernelGGL(k_gemm, dim3((unsigned)((M_ / 256) * (N_ / 256))), dim3(512),
                     131072, stream, xq, wq, b, out, gx_bits, gw_sum);
}

// Round 4
// 153.830 us; speedup vs baseline: 1.6575x; 1.1117x over previous
//
#include <hip/hip_runtime.h>
#include <hip/hip_bf16.h>
#include <stdint.h>

typedef __attribute__((ext_vector_type(4))) int i32x4;

static constexpr long M_ = 16384;   // 4*4096 rows of x
static constexpr long N_ = 2048;    // out_features
static constexpr long K_ = 2048;    // in_features

// ---- 256x256 8-phase i8 GEMM ----
// BM=BN=256, BK=128 i8. 8 waves (2M x 4N), 512 threads.
// LDS: [isb(A/B)][buf][ks][256 rows][64 B] = 128 KiB dynamic.
// Swizzle: row r, logical 16B-chunk c stored at physical chunk c ^ ((r>>1)&3).
// All row bases are multiples of 16 -> swizzle term depends only on lane&15,
// so every ds_read is one per-thread base + compile-time immediate offset.

#define GLOAD_LDS16(g, l)                                                          \
  __builtin_amdgcn_global_load_lds(                                               \
      (const __attribute__((address_space(1))) unsigned int*)(g),                 \
      (__attribute__((address_space(3))) unsigned int*)(l), 16, 0, 0)

// ---------------- fused stats: max|x| (blocks 0..2047), sum|W| (2048..2559) ----
__global__ __launch_bounds__(256) void k_stats(const float4* __restrict__ x,
                                               const float4* __restrict__ w,
                                               unsigned* __restrict__ gx_bits,
                                               double* __restrict__ gw_sum) {
  const int b = blockIdx.x;
  const int lane = threadIdx.x & 63, wv = threadIdx.x >> 6;
  if (b < 2048) {
    // n4 = 8388608 = 524288 * 16 ; unroll 2
    const long S = 524288;
    long i = (long)b * 256 + threadIdx.x;
    float m0 = 0.f, m1 = 0.f;
#pragma unroll
    for (int it = 0; it < 8; ++it) {
      float4 v0 = x[i];
      float4 v1 = x[i + S];
      m0 = fmaxf(m0, fmaxf(fmaxf(fabsf(v0.x), fabsf(v0.y)), fmaxf(fabsf(v0.z), fabsf(v0.w))));
      m1 = fmaxf(m1, fmaxf(fmaxf(fabsf(v1.x), fabsf(v1.y)), fmaxf(fabsf(v1.z), fabsf(v1.w))));
      i += 2 * S;
    }
    float m = fmaxf(m0, m1);
#pragma unroll
    for (int off = 32; off > 0; off >>= 1) m = fmaxf(m, __shfl_down(m, off));
    __shared__ float sm[4];
    if (lane == 0) sm[wv] = m;
    __syncthreads();
    if (threadIdx.x == 0) {
      float bm = fmaxf(fmaxf(sm[0], sm[1]), fmaxf(sm[2], sm[3]));
      atomicMax(gx_bits, __float_as_uint(bm));  // all >= 0
    }
  } else {
    // nw4 = 1048576 = 512*256*8
    const long S = 131072;
    long i = (long)(b - 2048) * 256 + threadIdx.x;
    double s = 0.0;
#pragma unroll
    for (int it = 0; it < 8; ++it) {
      float4 v = w[i];
      s += (double)fabsf(v.x) + (double)fabsf(v.y) + (double)fabsf(v.z) + (double)fabsf(v.w);
      i += S;
    }
#pragma unroll
    for (int off = 32; off > 0; off >>= 1) s += __shfl_down(s, off);
    __shared__ double sd[4];
    if (lane == 0) sd[wv] = s;
    __syncthreads();
    if (threadIdx.x == 0) atomicAdd(gw_sum, (sd[0] + sd[1]) + (sd[2] + sd[3]));
  }
}

// ---------------- fused quant: x (blocks 0..2047), W (2048..2559) ----------------
__global__ __launch_bounds__(256) void k_quant(const float4* __restrict__ x,
                                               const float4* __restrict__ w,
                                               char4* __restrict__ xq,
                                               char4* __restrict__ wq,
                                               const unsigned* __restrict__ gx_bits,
                                               const double* __restrict__ gw_sum) {
  const int b = blockIdx.x;
  if (b < 2048) {
    const double gx = (double)fmaxf(__uint_as_float(*gx_bits), 1e-8f);
    const double scale = 127.0 / gx;
    const long S = 524288;
    long i = (long)b * 256 + threadIdx.x;
#pragma unroll
    for (int it = 0; it < 16; ++it) {
      float4 v = x[i];
      char4 o;
      o.x = (signed char)(int)fmin(fmax(rint((double)v.x * scale), -127.0), 127.0);
      o.y = (signed char)(int)fmin(fmax(rint((double)v.y * scale), -127.0), 127.0);
      o.z = (signed char)(int)fmin(fmax(rint((double)v.z * scale), -127.0), 127.0);
      o.w = (signed char)(int)fmin(fmax(rint((double)v.w * scale), -127.0), 127.0);
      xq[i] = o;
      i += S;
    }
  } else {
    const double gw = fmax(*gw_sum * (1.0 / 4194304.0), 1e-8);
    const double inv = 1.0 / gw;
    const long S = 131072;
    long i = (long)(b - 2048) * 256 + threadIdx.x;
#pragma unroll
    for (int it = 0; it < 8; ++it) {
      float4 v = w[i];
      char4 o;
      o.x = (signed char)(int)fmin(fmax(rint((double)v.x * inv), -1.0), 1.0);
      o.y = (signed char)(int)fmin(fmax(rint((double)v.y * inv), -1.0), 1.0);
      o.z = (signed char)(int)fmin(fmax(rint((double)v.z * inv), -1.0), 1.0);
      o.w = (signed char)(int)fmin(fmax(rint((double)v.w * inv), -1.0), 1.0);
      wq[i] = o;
      i += S;
    }
  }
}

// ================= 8-phase GEMM =================

template <int ISB, int BUF, int KS>
__device__ __forceinline__ void stage2(signed char* lds, const signed char* gp, int kb,
                                       int go0, int ldsl0) {
  constexpr int R = ISB * 65536 + BUF * 32768 + KS * 16384;
  GLOAD_LDS16(gp + kb + go0, lds + R + ldsl0);
  GLOAD_LDS16(gp + kb + go0 + 32768, lds + R + ldsl0 + 1024);
}

template <int BUF, int KS, int MH, int SGB, int SGBUF, int SGKS, int VM>
__device__ __forceinline__ void phase(signed char* lds, const signed char* Ap,
                                      const signed char* Bp, int kb,
                                      const signed char* pA, const signed char* pB,
                                      int go0, int ldsl0, i32x4 acc[8][4], i32x4 b4[4]) {
  constexpr int RB = BUF * 32768 + KS * 16384;
  constexpr int RA = RB + MH * 4096;
  i32x4 a4[4];
  if (MH == 0) {
#pragma unroll
    for (int n = 0; n < 4; ++n) b4[n] = *(const i32x4*)(pB + RB + n * 1024);
  }
#pragma unroll
  for (int mm = 0; mm < 4; ++mm) a4[mm] = *(const i32x4*)(pA + RA + mm * 1024);

  if (SGB)
    stage2<1, SGBUF, SGKS>(lds, Bp, kb, go0, ldsl0);
  else
    stage2<0, SGBUF, SGKS>(lds, Ap, kb, go0, ldsl0);

  __builtin_amdgcn_s_barrier();
  asm volatile("s_waitcnt lgkmcnt(0)" ::: "memory");
  __builtin_amdgcn_s_setprio(1);
#pragma unroll
  for (int mm = 0; mm < 4; ++mm)
#pragma unroll
    for (int n = 0; n < 4; ++n)
      acc[MH * 4 + mm][n] =
          __builtin_amdgcn_mfma_i32_16x16x64_i8(a4[mm], b4[n], acc[MH * 4 + mm][n], 0, 0, 0);
  __builtin_amdgcn_s_setprio(0);
  if (VM) asm volatile("s_waitcnt vmcnt(8)" ::: "memory");
  __builtin_amdgcn_s_barrier();
}

__global__ __launch_bounds__(512, 2) void k_gemm(
    const signed char* __restrict__ Aq, const signed char* __restrict__ Bq,
    const float* __restrict__ bias, float* __restrict__ out,
    const unsigned* __restrict__ gx_bits, const double* __restrict__ gw_sum) {
  extern __shared__ signed char lds[];

  const int tid = threadIdx.x;
  const int lane = tid & 63;
  const int wid = tid >> 6;
  const int wave_m = wid >> 2;  // 0..1
  const int wave_n = wid & 3;   // 0..3
  const int l15 = lane & 15;

  // XCD swizzle: nwg = 512, 8 XCDs, 64 contiguous work-ids per XCD
  const int wg = (int)((blockIdx.x & 7) * 64 + (blockIdx.x >> 3));
  const int nblk = wg & 7;   // N_/256 = 8
  const int mblk = wg >> 3;  // 0..63
  const long brow = (long)mblk * 256;
  const long bcol = (long)nblk * 256;

  const signed char* Ap = Aq + brow * K_;
  const signed char* Bp = Bq + bcol * K_;

  // precomputed LDS read bases (per-thread constants)
  const int swz = ((lane >> 4) ^ ((l15 >> 1) & 3)) << 4;
  const signed char* pA = lds + (wave_m * 128 + l15) * 64 + swz;
  const signed char* pB = lds + 65536 + (wave_n * 64 + l15) * 64 + swz;

  // precomputed stage offsets: slot0 = wid*2, row r0 = wid*32 + (lane>>2),
  // logical chunk c0 = (lane&3) ^ ((lane>>3)&3); go1 = go0 + 16*K_.
  const int c0 = (lane & 3) ^ ((lane >> 3) & 3);
  const int go0 = (wid * 32 + (lane >> 2)) * (int)K_ + c0 * 16;
  const int ldsl0 = wid * 2048;  // slot0*1024

  i32x4 acc[8][4];
#pragma unroll
  for (int m = 0; m < 8; m++)
#pragma unroll
    for (int n = 0; n < 4; n++) acc[m][n] = (i32x4){0, 0, 0, 0};
  i32x4 b4[4];

  // prologue: tile0 (buf0) both halves, tile1 (buf1) ks0
  stage2<0, 0, 0>(lds, Ap, 0, go0, ldsl0);
  stage2<1, 0, 0>(lds, Bp, 0, go0, ldsl0);
  stage2<0, 0, 1>(lds, Ap, 64, go0, ldsl0);
  stage2<1, 0, 1>(lds, Bp, 64, go0, ldsl0);
  stage2<0, 1, 0>(lds, Ap, 128, go0, ldsl0);
  stage2<1, 1, 0>(lds, Bp, 128, go0, ldsl0);
  asm volatile("s_waitcnt vmcnt(0)" ::: "memory");
  __builtin_amdgcn_s_barrier();

  for (int kt = 0; kt < (int)K_; kt += 256) {
    const int k1h = (kt + 192) & 2047;  // tile t+1, ks1
    const int k2 = (kt + 256) & 2047;   // tile t+2
    const int k3 = (kt + 384) & 2047;   // tile t+3 (wraps harmlessly at the end)
    phase<0, 0, 0, 0, 1, 1, 0>(lds, Ap, Bp, k1h, pA, pB, go0, ldsl0, acc, b4);
    phase<0, 0, 1, 1, 1, 1, 1>(lds, Ap, Bp, k1h, pA, pB, go0, ldsl0, acc, b4);
    phase<0, 1, 0, 0, 0, 0, 0>(lds, Ap, Bp, k2, pA, pB, go0, ldsl0, acc, b4);
    phase<0, 1, 1, 1, 0, 0, 1>(lds, Ap, Bp, k2, pA, pB, go0, ldsl0, acc, b4);
    phase<1, 0, 0, 0, 0, 1, 0>(lds, Ap, Bp, k2 + 64, pA, pB, go0, ldsl0, acc, b4);
    phase<1, 0, 1, 1, 0, 1, 1>(lds, Ap, Bp, k2 + 64, pA, pB, go0, ldsl0, acc, b4);
    phase<1, 1, 0, 0, 1, 0, 0>(lds, Ap, Bp, k3, pA, pB, go0, ldsl0, acc, b4);
    phase<1, 1, 1, 1, 1, 0, 1>(lds, Ap, Bp, k3, pA, pB, go0, ldsl0, acc, b4);
  }

  const float gxf = fmaxf(__uint_as_float(*gx_bits), 1e-8f);
  const double gwd = fmax(*gw_sum * (1.0 / 4194304.0), 1e-8);
  const float alpha = (float)((double)gxf * gwd * (1.0 / 127.0));

#pragma unroll
  for (int n = 0; n < 4; ++n) {
    const long col = bcol + wave_n * 64 + n * 16 + l15;
    const float bv = bias[col];
#pragma unroll
    for (int m = 0; m < 8; ++m) {
      const long row0 = brow + wave_m * 128 + m * 16 + (lane >> 4) * 4;
#pragma unroll
      for (int r = 0; r < 4; ++r) {
        out[(row0 + r) * N_ + col] = (float)acc[m][n][r] * alpha + bv;
      }
    }
  }
}

extern "C" void kernel_launch(void* const* d_in, const int* in_sizes, int n_in,
                              void* d_out, int out_size, void* d_ws, size_t ws_size,
                              hipStream_t stream) {
  const float* x = (const float*)d_in[0];
  const float* W = (const float*)d_in[1];
  const float* b = (const float*)d_in[2];
  float* out = (float*)d_out;

  char* ws = (char*)d_ws;
  double* gw_sum = (double*)ws;            // 8 B
  unsigned* gx_bits = (unsigned*)(ws + 8); // 4 B
  signed char* xq = (signed char*)(ws + 256);                            // M*K i8 = 32 MiB
  signed char* wq = (signed char*)(ws + 256 + (size_t)M_ * (size_t)K_);  // N*K i8 = 4 MiB

  static bool attr_set = false;
  if (!attr_set) {
    (void)hipFuncSetAttribute(reinterpret_cast<const void*>(&k_gemm),
                              hipFuncAttributeMaxDynamicSharedMemorySize, 131072);
    attr_set = true;
  }

  hipMemsetAsync(ws, 0, 16, stream);
  hipLaunchKernelGGL(k_stats, dim3(2560), dim3(256), 0, stream,
                     (const float4*)x, (const float4*)W, gx_bits, gw_sum);
  hipLaunchKernelGGL(k_quant, dim3(2560), dim3(256), 0, stream,
                     (const float4*)x, (const float4*)W, (char4*)xq, (char4*)wq,
                     gx_bits, gw_sum);
  hipLaunchKernelGGL(k_gemm, dim3((unsigned)((M_ / 256) * (N_ / 256))), dim3(512),
                     131072, stream, xq, wq, b, out, gx_bits, gw_sum);
}